// Round 6
// baseline (151.634 us; speedup 1.0000x reference)
//
#include <hip/hip_runtime.h>
#include <hip/hip_cooperative_groups.h>

namespace cg = cooperative_groups;

#define D_MODEL 1024
#define N_MOD   4
#define EB      32     // e-chunks
#define ECHUNK  32     // e per chunk
#define EPW     8      // e per esub-wave
#define MAXGRID 1024   // desired co-resident grid: 4 blocks/CU x 256 CU

typedef float fx4 __attribute__((ext_vector_type(4)));

// ================= Cooperative fused kernel =================
//  Phase 1 (blocks 0..127): partial[m][eb][d] = sum_{e in eb} Wr[m][e]*Wg[e][d]
//  Phase 2 (blocks 0..15):  Weff[m][d] = sum_eb partial[m][eb][d]
//  Phase 3 (all blocks):    per-row logits -> softmax>0.5 -> discrete weights
__global__ __launch_bounds__(256, 4) void lora_router_fused(
    const float* __restrict__ h,        // [B, 1024]
    const fx4*   __restrict__ Wg4,      // [1024][256] fx4
    const float* __restrict__ Wr,       // [4][1024]
    float*       __restrict__ out,      // [4][B][4]
    float*       __restrict__ Weff,     // [4][1024]      (ws)
    fx4*         __restrict__ partial4, // [4][EB][256]   (ws)
    int B)
{
    cg::grid_group grid = cg::this_grid();
    const int t   = threadIdx.x;
    const int bid = blockIdx.x;

    __shared__ fx4 red[4][N_MOD][64];   // 16KB (phase 1 only)

    // ---------------- Phase 1 ----------------
    if (bid < EB * 4) {
        const int eb   = bid >> 2;
        const int dc   = bid & 3;
        const int esub = t >> 6;
        const int d4   = t & 63;
        const int d4g  = dc * 64 + d4;
        const int e0   = eb * ECHUNK + esub * EPW;

        fx4 acc[N_MOD];
        #pragma unroll
        for (int m = 0; m < N_MOD; ++m) acc[m] = (fx4)(0.f);

        #pragma unroll
        for (int k = 0; k < EPW; ++k) {
            const int e = e0 + k;
            const fx4 wg = Wg4[e * 256 + d4g];
            #pragma unroll
            for (int m = 0; m < N_MOD; ++m) {
                const float r = Wr[m * D_MODEL + e];   // wave-uniform scalar load
                acc[m] += r * wg;
            }
        }
        #pragma unroll
        for (int m = 0; m < N_MOD; ++m) red[esub][m][d4] = acc[m];
        __syncthreads();
        const int m2 = t >> 6;
        const fx4 s = red[0][m2][d4] + red[1][m2][d4] + red[2][m2][d4] + red[3][m2][d4];
        partial4[(m2 * EB + eb) * 256 + d4g] = s;
    }

    grid.sync();

    // ---------------- Phase 2 ----------------
    if (bid < 16) {
        const int idx = bid * 256 + t;               // 0..4095
        const int m = idx >> 10;
        const int d = idx & (D_MODEL - 1);
        const float* partial = (const float*)partial4;
        float s = 0.f;
        #pragma unroll
        for (int eb = 0; eb < EB; ++eb)
            s += partial[(m * EB + eb) * D_MODEL + d];
        Weff[idx] = s;
    }

    grid.sync();

    // ---------------- Phase 3 ----------------
    {
        const int lane = t & 63;
        const int wave = t >> 6;

        fx4 w4[N_MOD][4];
        const fx4* __restrict__ W4 = (const fx4*)Weff;
        #pragma unroll
        for (int m = 0; m < N_MOD; ++m)
            #pragma unroll
            for (int c = 0; c < 4; ++c)
                w4[m][c] = W4[m * 256 + c * 64 + lane];

        float4* __restrict__ out4 = (float4*)out;    // [4][B] float4s
        const int step = gridDim.x * 4;              // total waves

        for (int row = bid * 4 + wave; row < B; row += step) {
            const fx4* __restrict__ h4 = (const fx4*)(h + (size_t)row * D_MODEL);
            fx4 v[4];
            #pragma unroll
            for (int c = 0; c < 4; ++c) v[c] = h4[c * 64 + lane];

            float a[N_MOD] = {0.f, 0.f, 0.f, 0.f};
            #pragma unroll
            for (int c = 0; c < 4; ++c) {
                #pragma unroll
                for (int m = 0; m < N_MOD; ++m) {
                    a[m] = fmaf(v[c].x, w4[m][c].x, a[m]);
                    a[m] = fmaf(v[c].y, w4[m][c].y, a[m]);
                    a[m] = fmaf(v[c].z, w4[m][c].z, a[m]);
                    a[m] = fmaf(v[c].w, w4[m][c].w, a[m]);
                }
            }
            #pragma unroll
            for (int off = 32; off; off >>= 1) {
                #pragma unroll
                for (int m = 0; m < N_MOD; ++m)
                    a[m] += __shfl_xor(a[m], off, 64);
            }
            const float mx = fmaxf(fmaxf(a[0], a[1]), fmaxf(a[2], a[3]));
            float ex[N_MOD], S = 0.f;
            #pragma unroll
            for (int m = 0; m < N_MOD; ++m) { ex[m] = expf(a[m] - mx); S += ex[m]; }

            if (lane < N_MOD) {
                const bool hi = (2.f * ex[lane] > S);
                const float4 val = hi ? make_float4(0.5f, 0.5f, 0.f, 0.f)
                                      : make_float4(1.f, 0.f, 0.f, 0.f);
                out4[(size_t)lane * B + row] = val;
            }
        }
    }
}

// ================= Fallback: proven R4 3-kernel path =================
__global__ __launch_bounds__(256) void weff_partial_kernel(
    const fx4* __restrict__ Wg4, const float* __restrict__ Wr,
    fx4* __restrict__ partial4)
{
    const int t    = threadIdx.x;
    const int esub = t >> 6;
    const int d4   = t & 63;
    const int eb   = blockIdx.x;
    const int dc   = blockIdx.y;
    const int d4g  = dc * 64 + d4;
    const int e0   = eb * ECHUNK + esub * EPW;

    fx4 acc[N_MOD];
    #pragma unroll
    for (int m = 0; m < N_MOD; ++m) acc[m] = (fx4)(0.f);
    #pragma unroll
    for (int k = 0; k < EPW; ++k) {
        const int e = e0 + k;
        const fx4 wg = Wg4[e * 256 + d4g];
        #pragma unroll
        for (int m = 0; m < N_MOD; ++m)
            acc[m] += Wr[m * D_MODEL + e] * wg;
    }
    __shared__ fx4 red[4][N_MOD][64];
    #pragma unroll
    for (int m = 0; m < N_MOD; ++m) red[esub][m][d4] = acc[m];
    __syncthreads();
    const int m2 = t >> 6;
    const fx4 s = red[0][m2][d4] + red[1][m2][d4] + red[2][m2][d4] + red[3][m2][d4];
    partial4[(m2 * EB + eb) * 256 + d4g] = s;
}

__global__ __launch_bounds__(256) void weff_reduce_kernel(
    const float* __restrict__ partial, float* __restrict__ Weff)
{
    const int idx = blockIdx.x * 256 + threadIdx.x;
    const int m = idx >> 10;
    const int d = idx & (D_MODEL - 1);
    float s = 0.f;
    #pragma unroll
    for (int eb = 0; eb < EB; ++eb)
        s += partial[(m * EB + eb) * D_MODEL + d];
    Weff[idx] = s;
}

__global__ __launch_bounds__(256) void router_main_kernel(
    const float* __restrict__ h, const float* __restrict__ Weff,
    float* __restrict__ out, int B)
{
    const int lane = threadIdx.x & 63;
    const int wave = threadIdx.x >> 6;

    fx4 w4[N_MOD][4];
    const fx4* __restrict__ W4 = (const fx4*)Weff;
    #pragma unroll
    for (int m = 0; m < N_MOD; ++m)
        #pragma unroll
        for (int c = 0; c < 4; ++c)
            w4[m][c] = W4[m * 256 + c * 64 + lane];

    float4* __restrict__ out4 = (float4*)out;
    const int step = gridDim.x * 4;
    for (int row = blockIdx.x * 4 + wave; row < B; row += step) {
        const fx4* __restrict__ h4 = (const fx4*)(h + (size_t)row * D_MODEL);
        fx4 v[4];
        #pragma unroll
        for (int c = 0; c < 4; ++c) v[c] = h4[c * 64 + lane];
        float a[N_MOD] = {0.f, 0.f, 0.f, 0.f};
        #pragma unroll
        for (int c = 0; c < 4; ++c) {
            #pragma unroll
            for (int m = 0; m < N_MOD; ++m) {
                a[m] = fmaf(v[c].x, w4[m][c].x, a[m]);
                a[m] = fmaf(v[c].y, w4[m][c].y, a[m]);
                a[m] = fmaf(v[c].z, w4[m][c].z, a[m]);
                a[m] = fmaf(v[c].w, w4[m][c].w, a[m]);
            }
        }
        #pragma unroll
        for (int off = 32; off; off >>= 1) {
            #pragma unroll
            for (int m = 0; m < N_MOD; ++m)
                a[m] += __shfl_xor(a[m], off, 64);
        }
        const float mx = fmaxf(fmaxf(a[0], a[1]), fmaxf(a[2], a[3]));
        float ex[N_MOD], S = 0.f;
        #pragma unroll
        for (int m = 0; m < N_MOD; ++m) { ex[m] = expf(a[m] - mx); S += ex[m]; }
        if (lane < N_MOD) {
            const bool hi = (2.f * ex[lane] > S);
            const float4 val = hi ? make_float4(0.5f, 0.5f, 0.f, 0.f)
                                  : make_float4(1.f, 0.f, 0.f, 0.f);
            out4[(size_t)lane * B + row] = val;
        }
    }
}

extern "C" void kernel_launch(void* const* d_in, const int* in_sizes, int n_in,
                              void* d_out, int out_size, void* d_ws, size_t ws_size,
                              hipStream_t stream) {
    const float* h  = (const float*)d_in[0];   // [B, 1024]
    const fx4*   Wg = (const fx4*)d_in[1];     // [1024, 1024] floats
    const float* Wr = (const float*)d_in[2];   // [4, 1024]
    float* out = (float*)d_out;                // [4][B][4]

    int B = in_sizes[0] / D_MODEL;             // 32768

    float* Weff    = (float*)d_ws;                            // 16 KB
    fx4*   partial = (fx4*)((float*)d_ws + N_MOD * D_MODEL);  // 512 KB

    // Size the cooperative grid from the runtime's own occupancy answer.
    int blocksPerCU = 0;
    hipError_t qrc = hipOccupancyMaxActiveBlocksPerMultiprocessor(
        &blocksPerCU, lora_router_fused, 256, 0);

    bool coop_ok = false;
    if (qrc == hipSuccess && blocksPerCU >= 1) {
        int grid = blocksPerCU * 256;            // 256 CUs on MI355X
        if (grid > MAXGRID) grid = MAXGRID;
        if (grid >= EB * 4) {                    // phase 1 needs 128 blocks
            void* args[] = { (void*)&h, (void*)&Wg, (void*)&Wr, (void*)&out,
                             (void*)&Weff, (void*)&partial, (void*)&B };
            hipError_t rc = hipLaunchCooperativeKernel(
                (const void*)lora_router_fused, dim3(grid), dim3(256),
                args, 0, stream);
            coop_ok = (rc == hipSuccess);
        }
    }

    if (!coop_ok) {
        // Proven 3-kernel path (R4): identical math, identical output.
        dim3 g1(EB, 4);
        weff_partial_kernel<<<g1, 256, 0, stream>>>(Wg, Wr, partial);
        weff_reduce_kernel<<<(N_MOD * D_MODEL) / 256, 256, 0, stream>>>(
            (const float*)partial, Weff);
        router_main_kernel<<<1024, 256, 0, stream>>>(h, Weff, out, B);
    }
}

// Round 7
// 38.988 us; speedup vs baseline: 3.8893x; 3.8893x over previous
//
#include <hip/hip_runtime.h>

#define D_MODEL 1024
#define N_MOD   4

typedef float fx4 __attribute__((ext_vector_type(4)));

// ================= Kernel 1: fused Weff = Wr . Wg =================
// Grid: 16 blocks x 256 threads. Block b owns fx4-columns [16b, 16b+16).
// Each block loops over ALL 1024 e-rows of its column slice (Wg read exactly
// once grid-wide), reducing e across lanes/waves in-block. No second pass.
// Lane decomposition: c = lane&15 (column), s = lane>>4 (e-subgroup).
// e = wave*256 + s*64 + k, k = 0..63.
__global__ __launch_bounds__(256) void weff_fused_kernel(
    const fx4*   __restrict__ Wg4,   // [1024][256] fx4
    const float* __restrict__ Wr,    // [4][1024]
    fx4*         __restrict__ Weff4) // [4][256] fx4
{
    const int t    = threadIdx.x;
    const int wave = t >> 6;
    const int lane = t & 63;
    const int c    = lane & 15;
    const int s    = lane >> 4;
    const int col  = blockIdx.x * 16 + c;

    fx4 acc[N_MOD];
    #pragma unroll
    for (int m = 0; m < N_MOD; ++m) acc[m] = (fx4)(0.f);

    const int ebase = wave * 256 + s * 64;
    #pragma unroll 8
    for (int k = 0; k < 64; ++k) {
        const int e = ebase + k;
        const fx4 wg = Wg4[e * 256 + col];   // 4x 256B segments per wave inst
        #pragma unroll
        for (int m = 0; m < N_MOD; ++m)
            acc[m] += Wr[m * D_MODEL + e] * wg;  // Wr: 16KB, L1-hot
    }

    // Reduce over s (lane bits 4,5): lanes with s==0 end up with wave totals.
    #pragma unroll
    for (int off = 16; off <= 32; off <<= 1) {
        #pragma unroll
        for (int m = 0; m < N_MOD; ++m) {
            acc[m].x += __shfl_xor(acc[m].x, off, 64);
            acc[m].y += __shfl_xor(acc[m].y, off, 64);
            acc[m].z += __shfl_xor(acc[m].z, off, 64);
            acc[m].w += __shfl_xor(acc[m].w, off, 64);
        }
    }

    __shared__ fx4 red[4][N_MOD][16];   // 4KB
    if (s == 0) {
        #pragma unroll
        for (int m = 0; m < N_MOD; ++m) red[wave][m][c] = acc[m];
    }
    __syncthreads();

    if (t < 64) {
        const int m2 = t >> 4;
        const int c2 = t & 15;
        const fx4 sum = red[0][m2][c2] + red[1][m2][c2]
                      + red[2][m2][c2] + red[3][m2][c2];
        Weff4[m2 * 256 + blockIdx.x * 16 + c2] = sum;
    }
}

// ================= Kernel 2: main streaming pass (proven R4) =================
__global__ __launch_bounds__(256) void router_main_kernel(
    const float* __restrict__ h,     // [B, 1024]
    const float* __restrict__ Weff,  // [4, 1024]
    float* __restrict__ out,         // [4][B][4]
    int B)
{
    const int lane = threadIdx.x & 63;
    const int wave = threadIdx.x >> 6;

    fx4 w4[N_MOD][4];
    const fx4* __restrict__ W4 = (const fx4*)Weff;
    #pragma unroll
    for (int m = 0; m < N_MOD; ++m)
        #pragma unroll
        for (int c = 0; c < 4; ++c)
            w4[m][c] = W4[m * 256 + c * 64 + lane];

    float4* __restrict__ out4 = (float4*)out;        // [4][B] float4s
    const int step = gridDim.x * 4;

    for (int row = blockIdx.x * 4 + wave; row < B; row += step) {
        const fx4* __restrict__ h4 = (const fx4*)(h + (size_t)row * D_MODEL);
        fx4 v[4];
        #pragma unroll
        for (int c = 0; c < 4; ++c) v[c] = h4[c * 64 + lane];

        float a[N_MOD] = {0.f, 0.f, 0.f, 0.f};
        #pragma unroll
        for (int c = 0; c < 4; ++c) {
            #pragma unroll
            for (int m = 0; m < N_MOD; ++m) {
                a[m] = fmaf(v[c].x, w4[m][c].x, a[m]);
                a[m] = fmaf(v[c].y, w4[m][c].y, a[m]);
                a[m] = fmaf(v[c].z, w4[m][c].z, a[m]);
                a[m] = fmaf(v[c].w, w4[m][c].w, a[m]);
            }
        }
        #pragma unroll
        for (int off = 32; off; off >>= 1) {
            #pragma unroll
            for (int m = 0; m < N_MOD; ++m)
                a[m] += __shfl_xor(a[m], off, 64);
        }
        // prob_m > 0.5  <=>  2*exp(l_m - mx) > sum_j exp(l_j - mx)
        const float mx = fmaxf(fmaxf(a[0], a[1]), fmaxf(a[2], a[3]));
        float ex[N_MOD], S = 0.f;
        #pragma unroll
        for (int m = 0; m < N_MOD; ++m) { ex[m] = expf(a[m] - mx); S += ex[m]; }

        if (lane < N_MOD) {
            const bool hi = (2.f * ex[lane] > S);
            const float4 val = hi ? make_float4(0.5f, 0.5f, 0.f, 0.f)
                                  : make_float4(1.f, 0.f, 0.f, 0.f);
            out4[(size_t)lane * B + row] = val;
        }
    }
}

extern "C" void kernel_launch(void* const* d_in, const int* in_sizes, int n_in,
                              void* d_out, int out_size, void* d_ws, size_t ws_size,
                              hipStream_t stream) {
    const float* h  = (const float*)d_in[0];   // [B, 1024]
    const fx4*   Wg = (const fx4*)d_in[1];     // [1024, 1024] floats
    const float* Wr = (const float*)d_in[2];   // [4, 1024]
    float* out = (float*)d_out;                // [4][B][4]

    const int B = in_sizes[0] / D_MODEL;       // 32768

    float* Weff = (float*)d_ws;                // 16 KB

    weff_fused_kernel<<<16, 256, 0, stream>>>(Wg, Wr, (fx4*)Weff);
    router_main_kernel<<<2048, 256, 0, stream>>>(h, Weff, out, B);
}

// Round 8
// 33.647 us; speedup vs baseline: 4.5067x; 1.1587x over previous
//
#include <hip/hip_runtime.h>

#define D_MODEL 1024
#define N_MOD   4
#define EB      32     // e-chunks in stage 1
#define ECHUNK  32     // e per chunk
#define EPW     8      // e per esub-wave

typedef float fx4 __attribute__((ext_vector_type(4)));

// ============ Stage 1 (R4 verbatim): partial[m][eb][d] ============
__global__ __launch_bounds__(256) void weff_partial_kernel(
    const fx4* __restrict__ Wg4,   // [1024][256] fx4
    const float* __restrict__ Wr,  // [4][1024]
    fx4* __restrict__ partial4)    // [4][EB][256] fx4
{
    const int t    = threadIdx.x;
    const int esub = t >> 6;
    const int d4   = t & 63;
    const int eb   = blockIdx.x;
    const int dc   = blockIdx.y;
    const int d4g  = dc * 64 + d4;
    const int e0   = eb * ECHUNK + esub * EPW;

    fx4 acc[N_MOD];
    #pragma unroll
    for (int m = 0; m < N_MOD; ++m) acc[m] = (fx4)(0.f);
    #pragma unroll
    for (int k = 0; k < EPW; ++k) {
        const int e = e0 + k;
        const fx4 wg = Wg4[e * 256 + d4g];
        #pragma unroll
        for (int m = 0; m < N_MOD; ++m)
            acc[m] += Wr[m * D_MODEL + e] * wg;   // wave-uniform scalar Wr load
    }
    __shared__ fx4 red[4][N_MOD][64];
    #pragma unroll
    for (int m = 0; m < N_MOD; ++m) red[esub][m][d4] = acc[m];
    __syncthreads();
    const int m2 = t >> 6;
    const fx4 s = red[0][m2][d4] + red[1][m2][d4] + red[2][m2][d4] + red[3][m2][d4];
    partial4[(m2 * EB + eb) * 256 + d4g] = s;
}

// ============ Stage 2 (R4 verbatim): Weff[m][d] = sum_eb partial ============
__global__ __launch_bounds__(256) void weff_reduce_kernel(
    const float* __restrict__ partial, float* __restrict__ Weff)
{
    const int idx = blockIdx.x * 256 + threadIdx.x;
    const int m = idx >> 10;
    const int d = idx & (D_MODEL - 1);
    float s = 0.f;
    #pragma unroll
    for (int eb = 0; eb < EB; ++eb)
        s += partial[(m * EB + eb) * D_MODEL + d];
    Weff[idx] = s;
}

// ============ Main v2: 8 rows/wave, folded reduce, full-line stores ============
__global__ __launch_bounds__(256) void router_main_kernel(
    const float* __restrict__ h,     // [B, 1024]
    const float* __restrict__ Weff,  // [4, 1024]
    float* __restrict__ out,         // [4][B][4]
    int B)
{
    const int lane = threadIdx.x & 63;
    const int wave = threadIdx.x >> 6;

    fx4 w4[N_MOD][4];
    const fx4* __restrict__ W4 = (const fx4*)Weff;
    #pragma unroll
    for (int m = 0; m < N_MOD; ++m)
        #pragma unroll
        for (int c = 0; c < 4; ++c)
            w4[m][c] = W4[m * 256 + c * 64 + lane];

    float4* __restrict__ out4 = (float4*)out;   // [4][B] float4s
    const int wid  = blockIdx.x * 4 + wave;
    const int step = gridDim.x * 4 * 8;

    for (int row0 = wid * 8; row0 < B; row0 += step) {
        unsigned mask = 0;                       // bit i: row0+i is "hi" for module lane&3
        #pragma unroll
        for (int i = 0; i < 8; ++i) {
            const int row = row0 + i;
            const fx4* __restrict__ h4 = (const fx4*)(h + (size_t)row * D_MODEL);
            fx4 v[4];
            #pragma unroll
            for (int c = 0; c < 4; ++c) v[c] = h4[c * 64 + lane];

            float acc[N_MOD] = {0.f, 0.f, 0.f, 0.f};
            #pragma unroll
            for (int c = 0; c < 4; ++c) {
                #pragma unroll
                for (int m = 0; m < N_MOD; ++m) {
                    acc[m] = fmaf(v[c].x, w4[m][c].x, acc[m]);
                    acc[m] = fmaf(v[c].y, w4[m][c].y, acc[m]);
                    acc[m] = fmaf(v[c].z, w4[m][c].z, acc[m]);
                    acc[m] = fmaf(v[c].w, w4[m][c].w, acc[m]);
                }
            }
            // Fold 4 streams into lane%4, then butterfly: 7 shuffles total.
            const bool b0 = lane & 1;
            float a  = (b0 ? acc[1] : acc[0]) + __shfl_xor(b0 ? acc[0] : acc[1], 1, 64);
            float cc = (b0 ? acc[3] : acc[2]) + __shfl_xor(b0 ? acc[2] : acc[3], 1, 64);
            const bool b1 = lane & 2;
            float r  = (b1 ? cc : a) + __shfl_xor(b1 ? a : cc, 2, 64);
            r += __shfl_xor(r, 4, 64);
            r += __shfl_xor(r, 8, 64);
            r += __shfl_xor(r, 16, 64);
            r += __shfl_xor(r, 32, 64);
            // r = logit of module lane&3 (replicated across each 4-lane group)

            float mx = fmaxf(r, __shfl_xor(r, 1, 64));
            mx = fmaxf(mx, __shfl_xor(mx, 2, 64));
            const float ex = expf(r - mx);       // argmax lane: exactly 1.0
            float S = ex + __shfl_xor(ex, 1, 64);
            S = S + __shfl_xor(S, 2, 64);
            // prob_m > 0.5  <=>  m == argmax  &&  S < 2
            const bool hi = (r == mx) && (S < 2.0f);
            mask |= (hi ? 1u : 0u) << i;
        }
        // lanes 0-31 write 4 full 128B lines: module m = l>>3, row offset l&7
        const int m = lane >> 3;
        const int rs = lane & 7;
        const unsigned mm = __shfl(mask, m, 64); // lane m holds module m's mask
        if (lane < 32) {
            const bool hi = (mm >> rs) & 1;
            const float4 val = hi ? make_float4(0.5f, 0.5f, 0.f, 0.f)
                                  : make_float4(1.f, 0.f, 0.f, 0.f);
            out4[(size_t)m * B + row0 + rs] = val;
        }
    }
}

extern "C" void kernel_launch(void* const* d_in, const int* in_sizes, int n_in,
                              void* d_out, int out_size, void* d_ws, size_t ws_size,
                              hipStream_t stream) {
    const float* h  = (const float*)d_in[0];   // [B, 1024]
    const fx4*   Wg = (const fx4*)d_in[1];     // [1024, 1024] floats
    const float* Wr = (const float*)d_in[2];   // [4, 1024]
    float* out = (float*)d_out;                // [4][B][4]

    const int B = in_sizes[0] / D_MODEL;       // 32768

    float* Weff    = (float*)d_ws;                            // 16 KB
    fx4*   partial = (fx4*)((float*)d_ws + N_MOD * D_MODEL);  // 512 KB

    dim3 g1(EB, 4);
    weff_partial_kernel<<<g1, 256, 0, stream>>>(Wg, Wr, partial);
    weff_reduce_kernel<<<(N_MOD * D_MODEL) / 256, 256, 0, stream>>>(
        (const float*)partial, Weff);

    const int grid = (B + 8 * 4 - 1) / (8 * 4); // 1024 for B=32768
    router_main_kernel<<<grid, 256, 0, stream>>>(h, Weff, out, B);
}